// Round 6
// baseline (1335.070 us; speedup 1.0000x reference)
//
#include <hip/hip_runtime.h>
#include <math.h>

#define NUM_CODE 256
#define CODE_DIM 128
#define N_LAYERS 5
#define BB 16
#define TT 8192
#define MTOK (BB*TT)                    // 131072

#define QOFF   0ull
#define IOFF   83886080ull              // 16*128*8192*5
#define PPLOFF 84541440ull
#define LOSSOFF 84541445ull

// ws layout (bytes):
// [0, 5120)     : u32 cnt[5][256]
// [5120, 5160)  : double loss[5]
// [5160, 10280) : float ee2[5][256]   (numpy-pairwise |e_c|^2)
//
// Numeric model (BLAS-free numpy reference hypothesis):
//   dot_c  = numpy pairwise-8 mul/add over fl(r_k * e_k), k=0..127
//   ee2_c  = numpy pairwise-8 mul/add over fl(e_k^2)
//   dist   = fl( fl(rr2 + ee2_c) - fl(2*dot_c) ), argmin = first-min
//   residual chain: r = fl32(r - e[idx]) elementwise
// rr2's chain is provably irrelevant to comparisons (grid-shift invariance);
// pairwise-8 kept for consistency.

__global__ __launch_bounds__(256) void rvq_init_kernel(
        const float* __restrict__ emb,
        unsigned int* __restrict__ cnt,
        double* __restrict__ lossws,
        float* __restrict__ ee2)
{
    int g = blockIdx.x * 256 + threadIdx.x;
    if (g < N_LAYERS) lossws[g] = 0.0;
    if (g < N_LAYERS * NUM_CODE) {
        cnt[g] = 0u;
        const float* e = emb + (size_t)g * CODE_DIM;
        float s[8];
        #pragma unroll
        for (int j = 0; j < 8; ++j) s[j] = __fmul_rn(e[j], e[j]);
        #pragma unroll
        for (int i = 8; i < CODE_DIM; i += 8) {
            #pragma unroll
            for (int j = 0; j < 8; ++j)
                s[j] = __fadd_rn(s[j], __fmul_rn(e[i + j], e[i + j]));
        }
        ee2[g] = __fadd_rn(
            __fadd_rn(__fadd_rn(s[0], s[1]), __fadd_rn(s[2], s[3])),
            __fadd_rn(__fadd_rn(s[4], s[5]), __fadd_rn(s[6], s[7])));
    }
}

__global__ __launch_bounds__(256) void rvq_main_kernel(
        const float* __restrict__ x,
        const float* __restrict__ emb,
        float* __restrict__ out,
        unsigned int* __restrict__ cnt,
        double* __restrict__ lossws,
        const float* __restrict__ ee2ws)
{
    const int m = blockIdx.x * 256 + threadIdx.x;   // token id = b*T + t
    const int b = m >> 13;
    const int t = m & (TT - 1);
    const size_t xb = (size_t)b * (CODE_DIM * (size_t)TT) + (size_t)t;

    // residual in registers (static indexing only)
    float r[CODE_DIM];
    #pragma unroll
    for (int n = 0; n < CODE_DIM; ++n)
        r[n] = x[xb + (size_t)n * TT];

    float* __restrict__ outq = out + QOFF;
    float* __restrict__ outi = out + IOFF;

    int hist[N_LAYERS];

    for (int l = 0; l < N_LAYERS; ++l) {
        const float* __restrict__ el  = emb + (size_t)l * NUM_CODE * CODE_DIM;
        const float* __restrict__ e2l = ee2ws + l * NUM_CODE;

        // ---- rr2: numpy pairwise-8 (chain provably argmin-irrelevant) ----
        float sr[8];
        #pragma unroll
        for (int j = 0; j < 8; ++j) sr[j] = __fmul_rn(r[j], r[j]);
        #pragma unroll
        for (int i = 8; i < CODE_DIM; i += 8) {
            #pragma unroll
            for (int j = 0; j < 8; ++j)
                sr[j] = __fadd_rn(sr[j], __fmul_rn(r[i + j], r[i + j]));
        }
        const float rr2 = __fadd_rn(
            __fadd_rn(__fadd_rn(sr[0], sr[1]), __fadd_rn(sr[2], sr[3])),
            __fadd_rn(__fadd_rn(sr[4], sr[5]), __fadd_rn(sr[6], sr[7])));

        // ---- argmin: dot via numpy pairwise-8 mul/add tree ----
        float best = INFINITY;
        int bi = 0;
        for (int cb = 0; cb < NUM_CODE; cb += 4) {
            float s[4][8];
            #pragma unroll
            for (int i = 0; i < CODE_DIM / 8; ++i) {     // 16 k-blocks of 8
                #pragma unroll
                for (int c = 0; c < 4; ++c) {
                    const float* ec = el + (size_t)(cb + c) * CODE_DIM + 8 * i;
                    float4 ea = reinterpret_cast<const float4*>(ec)[0];
                    float4 eb = reinterpret_cast<const float4*>(ec)[1];
                    if (i == 0) {
                        s[c][0] = __fmul_rn(r[0], ea.x);
                        s[c][1] = __fmul_rn(r[1], ea.y);
                        s[c][2] = __fmul_rn(r[2], ea.z);
                        s[c][3] = __fmul_rn(r[3], ea.w);
                        s[c][4] = __fmul_rn(r[4], eb.x);
                        s[c][5] = __fmul_rn(r[5], eb.y);
                        s[c][6] = __fmul_rn(r[6], eb.z);
                        s[c][7] = __fmul_rn(r[7], eb.w);
                    } else {
                        s[c][0] = __fadd_rn(s[c][0], __fmul_rn(r[8*i+0], ea.x));
                        s[c][1] = __fadd_rn(s[c][1], __fmul_rn(r[8*i+1], ea.y));
                        s[c][2] = __fadd_rn(s[c][2], __fmul_rn(r[8*i+2], ea.z));
                        s[c][3] = __fadd_rn(s[c][3], __fmul_rn(r[8*i+3], ea.w));
                        s[c][4] = __fadd_rn(s[c][4], __fmul_rn(r[8*i+4], eb.x));
                        s[c][5] = __fadd_rn(s[c][5], __fmul_rn(r[8*i+5], eb.y));
                        s[c][6] = __fadd_rn(s[c][6], __fmul_rn(r[8*i+6], eb.z));
                        s[c][7] = __fadd_rn(s[c][7], __fmul_rn(r[8*i+7], eb.w));
                    }
                }
            }
            #pragma unroll
            for (int c = 0; c < 4; ++c) {
                float dot = __fadd_rn(
                    __fadd_rn(__fadd_rn(s[c][0], s[c][1]), __fadd_rn(s[c][2], s[c][3])),
                    __fadd_rn(__fadd_rn(s[c][4], s[c][5]), __fadd_rn(s[c][6], s[c][7])));
                float t1 = __fadd_rn(rr2, e2l[cb + c]);
                float di = __fsub_rn(t1, __fadd_rn(dot, dot));
                if (di < best) { best = di; bi = cb + c; }   // first-min
            }
        }

        hist[l] = bi;
        outi[(size_t)m * N_LAYERS + l] = (float)bi;
        atomicAdd(&cnt[l * NUM_CODE + bi], 1u);

        // ---- residual update: r = fl(r - e[bi]) elementwise ----
        const float4* q4 = reinterpret_cast<const float4*>(el + (size_t)bi * CODE_DIM);
        #pragma unroll
        for (int d = 0; d < CODE_DIM / 4; ++d) {
            float4 qv = q4[d];
            r[4 * d + 0] = __fsub_rn(r[4 * d + 0], qv.x);
            r[4 * d + 1] = __fsub_rn(r[4 * d + 1], qv.y);
            r[4 * d + 2] = __fsub_rn(r[4 * d + 2], qv.z);
            r[4 * d + 3] = __fsub_rn(r[4 * d + 3], qv.w);
        }

        // ---- latent loss term: sum r^2 (f64; threshold ~2% — slack ok) ----
        double ls = 0.0;
        #pragma unroll
        for (int n = 0; n < CODE_DIM; ++n)
            ls = fma((double)r[n], (double)r[n], ls);
        for (int o = 32; o > 0; o >>= 1)
            ls += __shfl_down(ls, o, 64);
        if ((threadIdx.x & 63) == 0)
            atomicAdd(&lossws[l], ls);
    }

    // ---------------- Phase B: quantized output, coalesced ----------------
    __shared__ float se[N_LAYERS][NUM_CODE][9];   // +1 pad
    const int NCH = 8;
    for (int chunk = 0; chunk < CODE_DIM / NCH; ++chunk) {
        const int n0 = chunk * NCH;
        __syncthreads();
        #pragma unroll
        for (int i = 0; i < (N_LAYERS * NUM_CODE * NCH) / 256; ++i) {   // 40
            int flat = i * 256 + threadIdx.x;
            int n = flat & (NCH - 1);
            int k = (flat >> 3) & (NUM_CODE - 1);
            int l = flat >> 11;
            se[l][k][n] = emb[((size_t)l * NUM_CODE + k) * CODE_DIM + n0 + n];
        }
        __syncthreads();
        #pragma unroll
        for (int n = 0; n < NCH; ++n) {
            float xv = x[xb + (size_t)(n0 + n) * TT];
            float rr = xv;
            float v[N_LAYERS];
            #pragma unroll
            for (int l = 0; l < N_LAYERS; ++l) {
                rr = __fsub_rn(rr, se[l][hist[l]][n]);
                v[l] = __fsub_rn(xv, rr);
            }
            size_t base = (xb + (size_t)(n0 + n) * TT) * N_LAYERS;
            outq[base + 0] = v[0];
            outq[base + 1] = v[1];
            outq[base + 2] = v[2];
            outq[base + 3] = v[3];
            outq[base + 4] = v[4];
        }
    }
}

__global__ __launch_bounds__(256) void rvq_finalize_kernel(
        const unsigned int* __restrict__ cnt,
        const double* __restrict__ lossws,
        float* __restrict__ out)
{
    __shared__ double sd[256];
    const int k = threadIdx.x;
    const double epsf = 1.1920928955078125e-07;  // float32 eps
    for (int l = 0; l < N_LAYERS; ++l) {
        float p = (float)cnt[l * NUM_CODE + k] / 131072.0f;   // exact (/2^17)
        double term = (double)p * log((double)p + epsf);
        sd[k] = term;
        __syncthreads();
        for (int s = 128; s > 0; s >>= 1) {
            if (k < s) sd[k] += sd[k + s];
            __syncthreads();
        }
        if (k == 0) out[PPLOFF + l] = (float)exp(-sd[0]);
        __syncthreads();
    }
    if (k == 0) {
        double tot = 0.0;
        for (int l = 0; l < N_LAYERS; ++l) tot += lossws[l];
        out[LOSSOFF] = (float)(tot / 16777216.0);   // / (B*N*T)
    }
}

extern "C" void kernel_launch(void* const* d_in, const int* in_sizes, int n_in,
                              void* d_out, int out_size, void* d_ws, size_t ws_size,
                              hipStream_t stream)
{
    const float* x   = (const float*)d_in[0];
    const float* emb = (const float*)d_in[1];
    float* out = (float*)d_out;

    unsigned int* cnt = (unsigned int*)d_ws;
    double* lossws    = (double*)((char*)d_ws + 5120);
    float* ee2ws      = (float*)((char*)d_ws + 5160);

    rvq_init_kernel<<<5, 256, 0, stream>>>(emb, cnt, lossws, ee2ws);
    rvq_main_kernel<<<MTOK / 256, 256, 0, stream>>>(x, emb, out, cnt, lossws, ee2ws);
    rvq_finalize_kernel<<<1, 256, 0, stream>>>(cnt, lossws, out);
}